// Round 2
// baseline (247.540 us; speedup 1.0000x reference)
//
#include <hip/hip_runtime.h>

// Problem constants (match reference)
constexpr int B = 8, C = 256, H = 96, W = 96;
constexpr int HW = H * W;          // 9216
constexpr int NPIX = B * HW;       // 73728
constexpr int PATCH = 21;
constexpr int HALF = PATCH / 2;    // 10
constexpr int DIL = 2;
constexpr int P2 = PATCH * PATCH;  // 441

// ---------------- Stage 1 ----------------
// D[b,y,x] = sum_c in1[b,c,y,x] * in2[b,c,y,x]
// blockDim (16,16). Each block: 64 consecutive pixels (16 lanes x float4),
// channels split 16-way across ty (16 channels each). 1152 blocks -> ~18
// waves/CU (4x the parallelism of the previous 288-block version), and
// float4 loads cut load-instruction count 4x.
__global__ __launch_bounds__(256) void dot_kernel(const float* __restrict__ a,
                                                  const float* __restrict__ b,
                                                  float* __restrict__ D) {
    __shared__ float4 red[16][16];   // [ty][tx]
    const int tx = threadIdx.x;      // 0..15 : x-quad within 64-pixel tile
    const int ty = threadIdx.y;      // 0..15 : channel group
    const int blk = blockIdx.x;      // 0..1151
    const int pix0 = blk * 64;       // 64 divides HW (9216) -> never straddles b
    const int bb = pix0 / HW;
    const int hw0 = pix0 - bb * HW;  // multiple of 64 -> 16B-aligned float4 base

    const int c0 = ty * 16;
    const float4* pa = (const float4*)(a + ((size_t)bb * C + c0) * HW + hw0) + tx;
    const float4* pb = (const float4*)(b + ((size_t)bb * C + c0) * HW + hw0) + tx;
    constexpr size_t CH_STRIDE = HW / 4;  // float4 stride between channels

    float4 acc = make_float4(0.f, 0.f, 0.f, 0.f);
    #pragma unroll 8
    for (int k = 0; k < 16; ++k) {
        float4 av = pa[k * CH_STRIDE];
        float4 bv = pb[k * CH_STRIDE];
        acc.x = fmaf(av.x, bv.x, acc.x);
        acc.y = fmaf(av.y, bv.y, acc.y);
        acc.z = fmaf(av.z, bv.z, acc.z);
        acc.w = fmaf(av.w, bv.w, acc.w);
    }
    red[ty][tx] = acc;
    __syncthreads();
    #pragma unroll
    for (int s = 8; s > 0; s >>= 1) {
        if (ty < s) {
            float4 o = red[ty + s][tx];
            float4 m = red[ty][tx];
            m.x += o.x; m.y += o.y; m.z += o.z; m.w += o.w;
            red[ty][tx] = m;
        }
        __syncthreads();
    }
    if (ty == 0) {
        ((float4*)(D + (size_t)bb * HW + hw0))[tx] = red[0][tx];
    }
}

// ---------------- Stage 2 ----------------
// out[b, py*21+px, y, x] = D[b, y+(py-10)*2, x+(px-10)*2]  (0 if OOB)
// One thread per 8 consecutive output x -> two float4 stores (32 B/thread),
// halving index-decode overhead per stored byte vs the 16 B version.
// D reads are cache-resident (37 KB per batch image).
__global__ __launch_bounds__(256) void scatter_kernel(const float* __restrict__ D,
                                                      float* __restrict__ out) {
    constexpr int W8 = W / 8;                    // 12
    constexpr int TOTAL = B * P2 * H * W8;       // 4,064,256
    int tid = blockIdx.x * blockDim.x + threadIdx.x;
    if (tid >= TOTAL) return;

    int x8 = tid % W8;
    int t  = tid / W8;
    int y  = t % H;  t /= H;
    int p  = t % P2; t /= P2;
    int bb = t;

    int py = p / PATCH;
    int px = p - py * PATCH;
    int sy = y + (py - HALF) * DIL;
    int x0 = x8 * 8;
    int sx0 = x0 + (px - HALF) * DIL;

    float4 v0 = make_float4(0.f, 0.f, 0.f, 0.f);
    float4 v1 = make_float4(0.f, 0.f, 0.f, 0.f);
    if (sy >= 0 && sy < H) {
        const float* row = D + (size_t)(bb * H + sy) * W;
        if (sx0 >= 0 && sx0 + 7 < W) {
            // fully interior: sx0 is even -> aligned float2 loads
            float2 a0 = *(const float2*)(row + sx0);
            float2 a1 = *(const float2*)(row + sx0 + 2);
            float2 a2 = *(const float2*)(row + sx0 + 4);
            float2 a3 = *(const float2*)(row + sx0 + 6);
            v0 = make_float4(a0.x, a0.y, a1.x, a1.y);
            v1 = make_float4(a2.x, a2.y, a3.x, a3.y);
        } else {
            float* pv0 = &v0.x;
            float* pv1 = &v1.x;
            #pragma unroll
            for (int i = 0; i < 4; ++i) {
                int sx = sx0 + i;
                if (sx >= 0 && sx < W) pv0[i] = row[sx];
            }
            #pragma unroll
            for (int i = 0; i < 4; ++i) {
                int sx = sx0 + 4 + i;
                if (sx >= 0 && sx < W) pv1[i] = row[sx];
            }
        }
    }
    float4* o = reinterpret_cast<float4*>(out) + (size_t)tid * 2;
    o[0] = v0;
    o[1] = v1;
}

extern "C" void kernel_launch(void* const* d_in, const int* in_sizes, int n_in,
                              void* d_out, int out_size, void* d_ws, size_t ws_size,
                              hipStream_t stream) {
    const float* in1 = (const float*)d_in[0];
    const float* in2 = (const float*)d_in[1];
    float* out = (float*)d_out;
    float* D = (float*)d_ws;  // NPIX floats = 294,912 bytes

    {
        dim3 threads(16, 16);
        int blocks = NPIX / 64;  // 1152
        dot_kernel<<<blocks, threads, 0, stream>>>(in1, in2, D);
    }
    {
        constexpr int TOTAL = B * P2 * H * (W / 8);
        int threads = 256;
        int blocks = (TOTAL + threads - 1) / threads;  // 15876
        scatter_kernel<<<blocks, threads, 0, stream>>>(D, out);
    }
}